// Round 1
// baseline (47.309 us; speedup 1.0000x reference)
//
#include <hip/hip_runtime.h>

// out[b,c] = bias[c] - sum_d |W[c,d] - x[b,d]|
// B=4096, C=512, D=256, fp32.
// Tiled distance-matrix kernel: BM=BN=64, DK=16, 256 threads, 4x4 per-thread tile.
// LDS stored transposed [d][row] so each fragment is one ds_read_b128.

#define B_SZ 4096
#define C_SZ 512
#define D_SZ 256

constexpr int BM = 64;   // batch rows per block
constexpr int BN = 64;   // classes per block
constexpr int DK = 16;   // k-chunk
constexpr int TM = 4;    // rows per thread
constexpr int TN = 4;    // cols per thread

__global__ __launch_bounds__(256)
void l1dist_kernel(const float* __restrict__ x,
                   const float* __restrict__ W,
                   const float* __restrict__ bias,
                   float* __restrict__ out) {
    __shared__ float xs[DK][BM];   // [d][row]
    __shared__ float ws[DK][BN];   // [d][col]

    const int tid  = threadIdx.x;      // 0..255
    const int tx   = tid & 15;         // col group 0..15
    const int ty   = tid >> 4;         // row group 0..15
    const int brow = blockIdx.y * BM;
    const int bcol = blockIdx.x * BN;

    float acc[TM][TN];
    #pragma unroll
    for (int i = 0; i < TM; ++i)
        #pragma unroll
        for (int j = 0; j < TN; ++j) acc[i][j] = 0.0f;

    // staging mapping: 4 threads per row, each loads a float4 of D
    const int srow = tid >> 2;         // 0..63
    const int sd4  = (tid & 3) * 4;    // 0,4,8,12

    for (int k0 = 0; k0 < D_SZ; k0 += DK) {
        float4 xv = *reinterpret_cast<const float4*>(
            &x[(brow + srow) * D_SZ + k0 + sd4]);
        float4 wv = *reinterpret_cast<const float4*>(
            &W[(bcol + srow) * D_SZ + k0 + sd4]);
        __syncthreads();   // previous-iter LDS reads done before overwrite
        xs[sd4 + 0][srow] = xv.x;
        xs[sd4 + 1][srow] = xv.y;
        xs[sd4 + 2][srow] = xv.z;
        xs[sd4 + 3][srow] = xv.w;
        ws[sd4 + 0][srow] = wv.x;
        ws[sd4 + 1][srow] = wv.y;
        ws[sd4 + 2][srow] = wv.z;
        ws[sd4 + 3][srow] = wv.w;
        __syncthreads();

        #pragma unroll
        for (int d = 0; d < DK; ++d) {
            float4 xf = *reinterpret_cast<const float4*>(&xs[d][ty * TM]);
            float4 wf = *reinterpret_cast<const float4*>(&ws[d][tx * TN]);
            float xa[TM] = {xf.x, xf.y, xf.z, xf.w};
            float wa[TN] = {wf.x, wf.y, wf.z, wf.w};
            #pragma unroll
            for (int i = 0; i < TM; ++i)
                #pragma unroll
                for (int j = 0; j < TN; ++j)
                    acc[i][j] += fabsf(xa[i] - wa[j]);
        }
    }

    // epilogue: out = bias - acc
    const int col0 = bcol + tx * TN;
    float4 bv = *reinterpret_cast<const float4*>(&bias[col0]);
    float ba[TN] = {bv.x, bv.y, bv.z, bv.w};
    #pragma unroll
    for (int i = 0; i < TM; ++i) {
        float4 o;
        o.x = ba[0] - acc[i][0];
        o.y = ba[1] - acc[i][1];
        o.z = ba[2] - acc[i][2];
        o.w = ba[3] - acc[i][3];
        *reinterpret_cast<float4*>(&out[(brow + ty * TM + i) * C_SZ + col0]) = o;
    }
}

extern "C" void kernel_launch(void* const* d_in, const int* in_sizes, int n_in,
                              void* d_out, int out_size, void* d_ws, size_t ws_size,
                              hipStream_t stream) {
    const float* x    = (const float*)d_in[0];
    const float* W    = (const float*)d_in[1];
    const float* bias = (const float*)d_in[2];
    float* out        = (float*)d_out;

    dim3 grid(C_SZ / BN, B_SZ / BM);   // (8, 64)
    dim3 block(256);
    l1dist_kernel<<<grid, block, 0, stream>>>(x, W, bias, out);
}

// Round 3
// 36.564 us; speedup vs baseline: 1.2938x; 1.2938x over previous
//
#include <hip/hip_runtime.h>

// out[b,c] = bias[c] - sum_d |W[c,d] - x[b,d]|   (B=4096, C=512, D=256, fp32 in/out)
//
// f16-packed inner loop: per 2 elements = v_pk_add_f16(neg) + v_and_b32 + v_dot2_f32_f16
// (1.5 VALU instr/element, f32 accumulation). LDS holds packed f16 pairs, [dpair][row]
// layout for broadcast-heavy b128 fragment reads. Double-buffered, conflict-free staging.

#define B_SZ 4096
#define C_SZ 512
#define D_SZ 256

constexpr int BM = 64;          // batch rows per block
constexpr int BN = 64;          // classes per block
constexpr int DK = 32;          // d-chunk (16 packed pairs)
constexpr int NP = DK / 2;      // packed pairs per chunk
constexpr int NCHUNK = D_SZ / DK;

// __fp16 vector — the exact type __builtin_amdgcn_cvt_pkrtz / fdot2 use
typedef __fp16 h2 __attribute__((ext_vector_type(2)));

__device__ __forceinline__ unsigned int pk(float a, float b) {
    h2 r = __builtin_amdgcn_cvt_pkrtz(a, b);
    return __builtin_bit_cast(unsigned int, r);
}

__device__ __forceinline__ float l1acc(unsigned int xu, unsigned int wu, float acc) {
    h2 xv = __builtin_bit_cast(h2, xu);
    h2 wv = __builtin_bit_cast(h2, wu);
    h2 d  = xv - wv;                                   // v_pk_add_f16 (neg mod)
    unsigned int du = __builtin_bit_cast(unsigned int, d) & 0x7fff7fffu;  // packed abs
    h2 da = __builtin_bit_cast(h2, du);
    h2 one = {(__fp16)1.0f, (__fp16)1.0f};
    return __builtin_amdgcn_fdot2(da, one, acc, false); // v_dot2_f32_f16
}

__global__ __launch_bounds__(256)
void l1dist_f16_kernel(const float* __restrict__ x,
                       const float* __restrict__ W,
                       const float* __restrict__ bias,
                       float* __restrict__ out) {
    __shared__ __align__(16) unsigned int xs[2][NP][BM];  // [buf][dpair][row]
    __shared__ __align__(16) unsigned int ws[2][NP][BN];  // [buf][dpair][col]

    const int tid  = threadIdx.x;        // 0..255
    const int tx   = tid & 15;           // col group
    const int ty   = tid >> 4;           // row group
    const int brow = blockIdx.y * BM;
    const int bcol = blockIdx.x * BN;

    // staging: one row per lane (conflict-free ds_write), 8 floats per thread per array
    const int r = tid & 63;              // row within tile
    const int g = tid >> 6;              // 0..3: which 8-float slice of the chunk

    const float* xrow = x + (brow + r) * D_SZ + g * 8;
    const float* wrow = W + (bcol + r) * D_SZ + g * 8;

    float acc[4][4];
    #pragma unroll
    for (int i = 0; i < 4; ++i)
        #pragma unroll
        for (int j = 0; j < 4; ++j) acc[i][j] = 0.0f;

    // prologue: stage chunk 0 into buf 0
    {
        float4 a0 = *reinterpret_cast<const float4*>(xrow + 0);
        float4 a1 = *reinterpret_cast<const float4*>(xrow + 4);
        float4 b0 = *reinterpret_cast<const float4*>(wrow + 0);
        float4 b1 = *reinterpret_cast<const float4*>(wrow + 4);
        xs[0][g * 4 + 0][r] = pk(a0.x, a0.y);
        xs[0][g * 4 + 1][r] = pk(a0.z, a0.w);
        xs[0][g * 4 + 2][r] = pk(a1.x, a1.y);
        xs[0][g * 4 + 3][r] = pk(a1.z, a1.w);
        ws[0][g * 4 + 0][r] = pk(b0.x, b0.y);
        ws[0][g * 4 + 1][r] = pk(b0.z, b0.w);
        ws[0][g * 4 + 2][r] = pk(b1.x, b1.y);
        ws[0][g * 4 + 3][r] = pk(b1.z, b1.w);
    }

    for (int ck = 0; ck < NCHUNK; ++ck) {
        const int cur = ck & 1;

        // prefetch next chunk into registers (hides HBM/L2 latency under compute)
        float4 a0, a1, b0, b1;
        if (ck + 1 < NCHUNK) {
            const float* xn = xrow + (ck + 1) * DK;
            const float* wn = wrow + (ck + 1) * DK;
            a0 = *reinterpret_cast<const float4*>(xn + 0);
            a1 = *reinterpret_cast<const float4*>(xn + 4);
            b0 = *reinterpret_cast<const float4*>(wn + 0);
            b1 = *reinterpret_cast<const float4*>(wn + 4);
        }

        __syncthreads();   // buf[cur] fully written; buf[cur^1] reads (prev iter) done

        #pragma unroll
        for (int dp = 0; dp < NP; ++dp) {
            uint4 xf = *reinterpret_cast<const uint4*>(&xs[cur][dp][ty * 4]);
            uint4 wf = *reinterpret_cast<const uint4*>(&ws[cur][dp][tx * 4]);
            unsigned int xa[4] = {xf.x, xf.y, xf.z, xf.w};
            unsigned int wa[4] = {wf.x, wf.y, wf.z, wf.w};
            #pragma unroll
            for (int i = 0; i < 4; ++i)
                #pragma unroll
                for (int j = 0; j < 4; ++j)
                    acc[i][j] = l1acc(xa[i], wa[j], acc[i][j]);
        }

        if (ck + 1 < NCHUNK) {
            const int nb = cur ^ 1;
            xs[nb][g * 4 + 0][r] = pk(a0.x, a0.y);
            xs[nb][g * 4 + 1][r] = pk(a0.z, a0.w);
            xs[nb][g * 4 + 2][r] = pk(a1.x, a1.y);
            xs[nb][g * 4 + 3][r] = pk(a1.z, a1.w);
            ws[nb][g * 4 + 0][r] = pk(b0.x, b0.y);
            ws[nb][g * 4 + 1][r] = pk(b0.z, b0.w);
            ws[nb][g * 4 + 2][r] = pk(b1.x, b1.y);
            ws[nb][g * 4 + 3][r] = pk(b1.z, b1.w);
        }
    }

    // epilogue: out = bias - acc  (f32)
    const int col0 = bcol + tx * 4;
    float4 bv = *reinterpret_cast<const float4*>(&bias[col0]);
    float ba[4] = {bv.x, bv.y, bv.z, bv.w};
    #pragma unroll
    for (int i = 0; i < 4; ++i) {
        float4 o;
        o.x = ba[0] - acc[i][0];
        o.y = ba[1] - acc[i][1];
        o.z = ba[2] - acc[i][2];
        o.w = ba[3] - acc[i][3];
        *reinterpret_cast<float4*>(&out[(brow + ty * 4 + i) * C_SZ + col0]) = o;
    }
}

extern "C" void kernel_launch(void* const* d_in, const int* in_sizes, int n_in,
                              void* d_out, int out_size, void* d_ws, size_t ws_size,
                              hipStream_t stream) {
    const float* x    = (const float*)d_in[0];
    const float* W    = (const float*)d_in[1];
    const float* bias = (const float*)d_in[2];
    float* out        = (float*)d_out;

    dim3 grid(C_SZ / BN, B_SZ / BM);   // (8, 64) = 512 blocks
    dim3 block(256);
    l1dist_f16_kernel<<<grid, block, 0, stream>>>(x, W, bias, out);
}

// Round 4
// 19.474 us; speedup vs baseline: 2.4293x; 1.8776x over previous
//
#include <hip/hip_runtime.h>

// out[b,c] = bias[c] - sum_d |W[c,d] - x[b,d]|   (B=4096, C=512, D=256, fp32 in/out)
//
// u16 fixed-point inner loop: quantize q = round((v+8)*4096) during staging; then
// v_sad_u16 computes |x0-w0|+|x1-w1|+acc in ONE instruction (0.5 VALU instr/element,
// exact u32 accumulation; quantization error <= 0.06 on the final sum).
// LDS packed u16 pairs, [dpair][row] layout; double-buffered, conflict-free staging.

#define B_SZ 4096
#define C_SZ 512
#define D_SZ 256

constexpr int BM = 64;          // batch rows per block
constexpr int BN = 64;          // classes per block
constexpr int DK = 32;          // d-chunk (16 packed pairs)
constexpr int NP = DK / 2;      // packed pairs per chunk
constexpr int NCHUNK = D_SZ / DK;

__device__ __forceinline__ unsigned int sad16(unsigned int a, unsigned int b, unsigned int c) {
#if __has_builtin(__builtin_amdgcn_sad_u16)
    return __builtin_amdgcn_sad_u16(a, b, c);
#else
    unsigned int d;
    asm("v_sad_u16 %0, %1, %2, %3" : "=v"(d) : "v"(a), "v"(b), "v"(c));
    return d;
#endif
}

// quantize: (v + 8) * 4096, rounded (the +0.5 is folded into the fma addend)
__device__ __forceinline__ unsigned int q16(float v) {
    return (unsigned int)(v * 4096.0f + 32768.5f);   // v_fma_f32 + v_cvt_u32_f32
}
__device__ __forceinline__ unsigned int qpk(float a, float b) {
    return q16(a) | (q16(b) << 16);                  // + v_lshl_or_b32
}

__global__ __launch_bounds__(256)
void l1dist_sad_kernel(const float* __restrict__ x,
                       const float* __restrict__ W,
                       const float* __restrict__ bias,
                       float* __restrict__ out) {
    __shared__ __align__(16) unsigned int xs[2][NP][BM];  // [buf][dpair][row]
    __shared__ __align__(16) unsigned int ws[2][NP][BN];  // [buf][dpair][col]

    const int tid  = threadIdx.x;        // 0..255
    const int tx   = tid & 15;           // col group
    const int ty   = tid >> 4;           // row group
    const int brow = blockIdx.y * BM;
    const int bcol = blockIdx.x * BN;

    // staging: one row per lane (conflict-free ds_write), 8 floats per thread per array
    const int r = tid & 63;              // row within tile
    const int g = tid >> 6;              // 0..3: which 8-float slice of the chunk

    const float* xrow = x + (brow + r) * D_SZ + g * 8;
    const float* wrow = W + (bcol + r) * D_SZ + g * 8;

    unsigned int acc[4][4];
    #pragma unroll
    for (int i = 0; i < 4; ++i)
        #pragma unroll
        for (int j = 0; j < 4; ++j) acc[i][j] = 0u;

    // prologue: stage chunk 0 into buf 0
    {
        float4 a0 = *reinterpret_cast<const float4*>(xrow + 0);
        float4 a1 = *reinterpret_cast<const float4*>(xrow + 4);
        float4 b0 = *reinterpret_cast<const float4*>(wrow + 0);
        float4 b1 = *reinterpret_cast<const float4*>(wrow + 4);
        xs[0][g * 4 + 0][r] = qpk(a0.x, a0.y);
        xs[0][g * 4 + 1][r] = qpk(a0.z, a0.w);
        xs[0][g * 4 + 2][r] = qpk(a1.x, a1.y);
        xs[0][g * 4 + 3][r] = qpk(a1.z, a1.w);
        ws[0][g * 4 + 0][r] = qpk(b0.x, b0.y);
        ws[0][g * 4 + 1][r] = qpk(b0.z, b0.w);
        ws[0][g * 4 + 2][r] = qpk(b1.x, b1.y);
        ws[0][g * 4 + 3][r] = qpk(b1.z, b1.w);
    }

    for (int ck = 0; ck < NCHUNK; ++ck) {
        const int cur = ck & 1;

        // prefetch next chunk into registers (hides HBM/L2 latency under compute)
        float4 a0, a1, b0, b1;
        if (ck + 1 < NCHUNK) {
            const float* xn = xrow + (ck + 1) * DK;
            const float* wn = wrow + (ck + 1) * DK;
            a0 = *reinterpret_cast<const float4*>(xn + 0);
            a1 = *reinterpret_cast<const float4*>(xn + 4);
            b0 = *reinterpret_cast<const float4*>(wn + 0);
            b1 = *reinterpret_cast<const float4*>(wn + 4);
        }

        __syncthreads();   // buf[cur] fully written; buf[cur^1] reads (prev iter) done

        #pragma unroll
        for (int dp = 0; dp < NP; ++dp) {
            uint4 xf = *reinterpret_cast<const uint4*>(&xs[cur][dp][ty * 4]);
            uint4 wf = *reinterpret_cast<const uint4*>(&ws[cur][dp][tx * 4]);
            unsigned int xa[4] = {xf.x, xf.y, xf.z, xf.w};
            unsigned int wa[4] = {wf.x, wf.y, wf.z, wf.w};
            #pragma unroll
            for (int i = 0; i < 4; ++i)
                #pragma unroll
                for (int j = 0; j < 4; ++j)
                    acc[i][j] = sad16(xa[i], wa[j], acc[i][j]);
        }

        if (ck + 1 < NCHUNK) {
            const int nb = cur ^ 1;
            xs[nb][g * 4 + 0][r] = qpk(a0.x, a0.y);
            xs[nb][g * 4 + 1][r] = qpk(a0.z, a0.w);
            xs[nb][g * 4 + 2][r] = qpk(a1.x, a1.y);
            xs[nb][g * 4 + 3][r] = qpk(a1.z, a1.w);
            ws[nb][g * 4 + 0][r] = qpk(b0.x, b0.y);
            ws[nb][g * 4 + 1][r] = qpk(b0.z, b0.w);
            ws[nb][g * 4 + 2][r] = qpk(b1.x, b1.y);
            ws[nb][g * 4 + 3][r] = qpk(b1.z, b1.w);
        }
    }

    // epilogue: out = bias - acc/4096  (f32)
    const int col0 = bcol + tx * 4;
    float4 bv = *reinterpret_cast<const float4*>(&bias[col0]);
    float ba[4] = {bv.x, bv.y, bv.z, bv.w};
    constexpr float inv_scale = 1.0f / 4096.0f;
    #pragma unroll
    for (int i = 0; i < 4; ++i) {
        float4 o;
        o.x = ba[0] - (float)acc[i][0] * inv_scale;
        o.y = ba[1] - (float)acc[i][1] * inv_scale;
        o.z = ba[2] - (float)acc[i][2] * inv_scale;
        o.w = ba[3] - (float)acc[i][3] * inv_scale;
        *reinterpret_cast<float4*>(&out[(brow + ty * 4 + i) * C_SZ + col0]) = o;
    }
}

extern "C" void kernel_launch(void* const* d_in, const int* in_sizes, int n_in,
                              void* d_out, int out_size, void* d_ws, size_t ws_size,
                              hipStream_t stream) {
    const float* x    = (const float*)d_in[0];
    const float* W    = (const float*)d_in[1];
    const float* bias = (const float*)d_in[2];
    float* out        = (float*)d_out;

    dim3 grid(C_SZ / BN, B_SZ / BM);   // (8, 64) = 512 blocks
    dim3 block(256);
    l1dist_sad_kernel<<<grid, block, 0, stream>>>(x, W, bias, out);
}